// Round 4
// baseline (770.065 us; speedup 1.0000x reference)
//
#include <hip/hip_runtime.h>
#include <cstddef>
#include <cstdint>

typedef unsigned short u16;

constexpr int BATCH = 4;
constexpr int Lq = 4096;
constexpr int Lk = 4096;
constexpr int D  = 512;

constexpr int BM = 128, BN = 128, BK = 32;
constexpr int LDA = 40;   // fallback-path LDS stride

using bf16x8 = __attribute__((ext_vector_type(8))) short;
using f32x4  = __attribute__((ext_vector_type(4))) float;

__device__ inline u16 f32_to_bf16_rne(float x) {
    uint32_t u = __builtin_bit_cast(uint32_t, x);
    u += 0x7fff + ((u >> 16) & 1);
    return (u16)(u >> 16);
}
__device__ inline float bf16_bits_to_f32(u16 h) {
    uint32_t u = ((uint32_t)h) << 16;
    return __builtin_bit_cast(float, u);
}
__device__ inline void split2(float x, float y, uint32_t& hi, uint32_t& lo) {
    u16 hx = f32_to_bf16_rne(x);
    u16 hy = f32_to_bf16_rne(y);
    u16 lx = f32_to_bf16_rne(x - bf16_bits_to_f32(hx));
    u16 ly = f32_to_bf16_rne(y - bf16_bits_to_f32(hy));
    hi = (uint32_t)hx | ((uint32_t)hy << 16);
    lo = (uint32_t)lx | ((uint32_t)ly << 16);
}
__device__ inline uint32_t pack2_bf16(float x, float y) {
    return (uint32_t)f32_to_bf16_rne(x) | ((uint32_t)f32_to_bf16_rne(y) << 16);
}
// async global->LDS, 16B/lane; LDS dest is wave-uniform base + lane*16
__device__ inline void gld16(const u16* g, u16* l) {
    __builtin_amdgcn_global_load_lds(
        (const __attribute__((address_space(1))) void*)g,
        (__attribute__((address_space(3))) void*)l, 16, 0, 0);
}
__device__ inline f32x4 mfma16(bf16x8 a, bf16x8 b, f32x4 c) {
    return __builtin_amdgcn_mfma_f32_16x16x32_bf16(a, b, c, 0, 0, 0);
}

// ------- pre-split both tensors: fp32 -> bf16 hi + bf16 lo (one launch) ----
__global__ __launch_bounds__(256)
void split_qv_bf16(const float* __restrict__ Q, const float* __restrict__ V,
                   u16* __restrict__ Qhi, u16* __restrict__ Qlo,
                   u16* __restrict__ Vhi, u16* __restrict__ Vlo, int n4)
{
    int i = blockIdx.x * 256 + threadIdx.x;
    const float* src;
    u16 *hi, *lo;
    if (i < n4) { src = Q; hi = Qhi; lo = Qlo; }
    else        { src = V; hi = Vhi; lo = Vlo; i -= n4; }
    const float4 v = ((const float4*)src)[i];
    uint2 h, l;
    split2(v.x, v.y, h.x, l.x);
    split2(v.z, v.w, h.y, l.y);
    ((uint2*)hi)[i] = h;
    ((uint2*)lo)[i] = l;
}

// ---------------- V^T (bf16) into workspace: VT[b][d][lk] -------------------
__global__ __launch_bounds__(256)
void transpose_v_bf16(const float* __restrict__ V, u16* __restrict__ VT)
{
    __shared__ float tile[32][33];
    const int b = blockIdx.z;
    const float* in = V + (size_t)b * Lk * D;
    u16* out = VT + (size_t)b * D * Lk;
    const int lk0 = blockIdx.x * 32;
    const int d0  = blockIdx.y * 32;
    const int c  = threadIdx.x & 31;
    const int r0 = threadIdx.x >> 5;
    #pragma unroll
    for (int i = 0; i < 4; ++i) {
        const int r = r0 + 8 * i;
        tile[r][c] = in[(size_t)(lk0 + r) * D + d0 + c];
    }
    __syncthreads();
    #pragma unroll
    for (int i = 0; i < 4; ++i) {
        const int r = r0 + 8 * i;
        out[(size_t)(d0 + r) * Lk + lk0 + c] = f32_to_bf16_rne(tile[c][r]);
    }
}

// ===== GEMM1: S = Q@V^T, 256x256 tile, 8 waves, 4-phase/K-tile pipeline ====
// (round-1 version, verified 201-204 us / 0 bank conflicts — unchanged)
__global__ __launch_bounds__(512, 2)
void gemm1_8p(const u16* __restrict__ Qhi, const u16* __restrict__ Qlo,
              const u16* __restrict__ Vhi, const u16* __restrict__ Vlo,
              float* __restrict__ Sg)
{
    constexpr int K  = D;        // 512
    constexpr int NT = K / 32;   // 16 K-tiles
    // [buf][Ahi|Alo|Bhi|Blo][256 rows][32 k] u16 = 128 KiB
    __shared__ u16 lds[2 * 4 * 8192];

    const int b = blockIdx.z;
    const u16* Ah = Qhi + (size_t)b * Lq * K;
    const u16* Al = Qlo + (size_t)b * Lq * K;
    const u16* Bh = Vhi + (size_t)b * Lk * K;
    const u16* Bl = Vlo + (size_t)b * Lk * K;
    float* C = Sg + (size_t)b * Lq * Lk;

    const int m0 = blockIdx.y * 256;
    const int n0 = blockIdx.x * 256;
    const int t = threadIdx.x, lane = t & 63, w = t >> 6;
    const int wm = (w >> 2) * 128, wn = (w & 3) * 64;
    const int fr = lane & 15, fq = lane >> 4;

    const int cg   = (lane & 3) ^ ((lane >> 3) & 3);   // inverse-swizzled k-chunk
    const int rsub = lane >> 2;
    const int offA0 = (m0 + w * 32 + rsub) * K + cg * 8;
    const int offA1 = offA0 + 16 * K;
    const int offB0 = (n0 + w * 32 + rsub) * K + cg * 8;
    const int offB1 = offB0 + 16 * K;
    const int ch = w * 1024;   // u16: this wave's chunk base

    const int swzc = fq ^ ((fr >> 1) & 3);
    const int aRd = (wm + fr) * 64 + swzc * 16;   // bytes within Ahi region
    const int bRd = (wn + fr) * 64 + swzc * 16;   // bytes within Bhi region

    f32x4 acc[8][4] = {};
    bf16x8 aH[4], aL[4], bH[4], bL[4];

    // prologue: stage K-tile 0 into buf 0
    {
        u16* a = &lds[ch];
        gld16(Ah + offA0, a);
        gld16(Ah + offA1, a + 512);
        gld16(Al + offA0, a + 8192);
        gld16(Al + offA1, a + 8192 + 512);
        u16* v = &lds[16384 + ch];
        gld16(Bh + offB0, v);
        gld16(Bh + offB1, v + 512);
        gld16(Bl + offB0, v + 8192);
        gld16(Bl + offB1, v + 8192 + 512);
    }
    asm volatile("s_waitcnt vmcnt(0)" ::: "memory");
    __builtin_amdgcn_s_barrier();
    __builtin_amdgcn_sched_barrier(0);

    for (int kt = 0; kt < NT; ++kt) {
        const int cur = kt & 1;
        const char* ls = (const char*)lds + cur * 65536;
        const int kn = (kt + 1) * 32;
        const int nb = (cur ^ 1) * 32768;   // u16 index of next buffer

        // ---- phase 0: frags A(mh0) + B(n0,n1); prefetch next A ----
        #pragma unroll
        for (int m = 0; m < 4; ++m) {
            aH[m] = *(const bf16x8*)(ls + aRd + m * 1024);
            aL[m] = *(const bf16x8*)(ls + 16384 + aRd + m * 1024);
        }
        #pragma unroll
        for (int n = 0; n < 2; ++n) {
            bH[n] = *(const bf16x8*)(ls + 32768 + bRd + n * 1024);
            bL[n] = *(const bf16x8*)(ls + 49152 + bRd + n * 1024);
        }
        if (kt < NT - 1) {
            u16* a = &lds[nb + ch];
            gld16(Ah + offA0 + kn, a);
            gld16(Ah + offA1 + kn, a + 512);
            gld16(Al + offA0 + kn, a + 8192);
            gld16(Al + offA1 + kn, a + 8192 + 512);
        }
        __builtin_amdgcn_s_barrier();
        asm volatile("s_waitcnt lgkmcnt(0)" ::: "memory");
        __builtin_amdgcn_sched_barrier(0);
        __builtin_amdgcn_s_setprio(1);
        #pragma unroll
        for (int m = 0; m < 4; ++m)
            #pragma unroll
            for (int n = 0; n < 2; ++n) {
                acc[m][n] = mfma16(aH[m], bH[n], acc[m][n]);
                acc[m][n] = mfma16(aH[m], bL[n], acc[m][n]);
                acc[m][n] = mfma16(aL[m], bH[n], acc[m][n]);
            }
        __builtin_amdgcn_s_setprio(0);
        __builtin_amdgcn_s_barrier();
        __builtin_amdgcn_sched_barrier(0);

        // ---- phase 1: frags B(n2,n3); prefetch next B ----
        #pragma unroll
        for (int n = 2; n < 4; ++n) {
            bH[n] = *(const bf16x8*)(ls + 32768 + bRd + n * 1024);
            bL[n] = *(const bf16x8*)(ls + 49152 + bRd + n * 1024);
        }
        if (kt < NT - 1) {
            u16* v = &lds[nb + 16384 + ch];
            gld16(Bh + offB0 + kn, v);
            gld16(Bh + offB1 + kn, v + 512);
            gld16(Bl + offB0 + kn, v + 8192);
            gld16(Bl + offB1 + kn, v + 8192 + 512);
        }
        __builtin_amdgcn_s_barrier();
        asm volatile("s_waitcnt lgkmcnt(0)" ::: "memory");
        __builtin_amdgcn_sched_barrier(0);
        __builtin_amdgcn_s_setprio(1);
        #pragma unroll
        for (int m = 0; m < 4; ++m)
            #pragma unroll
            for (int n = 2; n < 4; ++n) {
                acc[m][n] = mfma16(aH[m], bH[n], acc[m][n]);
                acc[m][n] = mfma16(aH[m], bL[n], acc[m][n]);
                acc[m][n] = mfma16(aL[m], bH[n], acc[m][n]);
            }
        __builtin_amdgcn_s_setprio(0);
        __builtin_amdgcn_s_barrier();
        __builtin_amdgcn_sched_barrier(0);

        // ---- phase 2: frags A(mh1) ----
        #pragma unroll
        for (int m = 0; m < 4; ++m) {
            aH[m] = *(const bf16x8*)(ls + 4096 + aRd + m * 1024);
            aL[m] = *(const bf16x8*)(ls + 16384 + 4096 + aRd + m * 1024);
        }
        __builtin_amdgcn_s_barrier();
        asm volatile("s_waitcnt lgkmcnt(0)" ::: "memory");
        __builtin_amdgcn_sched_barrier(0);
        __builtin_amdgcn_s_setprio(1);
        #pragma unroll
        for (int m = 0; m < 4; ++m)
            #pragma unroll
            for (int n = 0; n < 2; ++n) {
                acc[4 + m][n] = mfma16(aH[m], bH[n], acc[4 + m][n]);
                acc[4 + m][n] = mfma16(aH[m], bL[n], acc[4 + m][n]);
                acc[4 + m][n] = mfma16(aL[m], bH[n], acc[4 + m][n]);
            }
        __builtin_amdgcn_s_setprio(0);
        __builtin_amdgcn_s_barrier();
        __builtin_amdgcn_sched_barrier(0);

        // ---- phase 3: last quadrant; tile-boundary drain (only vmcnt) ----
        __builtin_amdgcn_s_setprio(1);
        #pragma unroll
        for (int m = 0; m < 4; ++m)
            #pragma unroll
            for (int n = 2; n < 4; ++n) {
                acc[4 + m][n] = mfma16(aH[m], bH[n], acc[4 + m][n]);
                acc[4 + m][n] = mfma16(aH[m], bL[n], acc[4 + m][n]);
                acc[4 + m][n] = mfma16(aL[m], bH[n], acc[4 + m][n]);
            }
        __builtin_amdgcn_s_setprio(0);
        asm volatile("s_waitcnt vmcnt(0)" ::: "memory");
        __builtin_amdgcn_s_barrier();
        __builtin_amdgcn_sched_barrier(0);
    }

    const int rowb = m0 + wm + fq * 4;
    const int colb = n0 + wn + fr;
    #pragma unroll
    for (int mi = 0; mi < 8; ++mi)
        #pragma unroll
        for (int ni = 0; ni < 4; ++ni)
            #pragma unroll
            for (int r = 0; r < 4; ++r)
                C[(size_t)(rowb + mi * 16 + r) * Lk + colb + ni * 16] = acc[mi][ni][r];
}

// -------- row stats: one row per wave, read-only -> rowM / rowInv ----------
__global__ __launch_bounds__(256)
void row_stats(const float* __restrict__ S, float* __restrict__ rowM,
               float* __restrict__ rowI)
{
    const size_t row = (size_t)blockIdx.x * 4 + (threadIdx.x >> 6);
    const int l = threadIdx.x & 63;
    const float* p = S + row * (size_t)Lk;

    float4 v[16];
    #pragma unroll
    for (int j = 0; j < 16; ++j) v[j] = ((const float4*)p)[l + j * 64];

    float m = -3.0e38f;
    #pragma unroll
    for (int j = 0; j < 16; ++j)
        m = fmaxf(m, fmaxf(fmaxf(v[j].x, v[j].y), fmaxf(v[j].z, v[j].w)));
    #pragma unroll
    for (int off = 32; off > 0; off >>= 1) m = fmaxf(m, __shfl_xor(m, off));

    float s = 0.f;
    #pragma unroll
    for (int j = 0; j < 16; ++j) {
        s += __expf(v[j].x - m);
        s += __expf(v[j].y - m);
        s += __expf(v[j].z - m);
        s += __expf(v[j].w - m);
    }
    #pragma unroll
    for (int off = 32; off > 0; off >>= 1) s += __shfl_xor(s, off);

    if (l == 0) {
        rowM[row] = m;
        rowI[row] = 1.0f / s;
    }
}

// ===== fused finalize+PV: attn = exp(S-m)*inv (in place) and ctx = P@V =====
// Tile: 32 q-rows x all 512 ctx-cols -> each S element read exactly once.
// 512 thr / 8 waves; wave w owns ctx cols [w*64, w*64+64).
// LDS: sB = VT[512][64k] bf16 (64 KB, gld16-staged, XOR-chunk swizzle via
// inverse-swizzled global source); sA = P[32][64k] bf16 (8 KB, reg-staged
// with the same swizzle on the ds_write side). 72 KB -> 2 blocks/CU.
__global__ __launch_bounds__(512, 4)
void fused_pv(float* __restrict__ S, const u16* __restrict__ VTg,
              float* __restrict__ ctx, const float* __restrict__ rowM,
              const float* __restrict__ rowI)
{
    constexpr int NT = Lk / 64;   // 64 K-steps
    __shared__ u16 sB[512 * 64];
    __shared__ u16 sA[32 * 64];

    // block decode: i&7 -> XCD; batch b pinned to XCDs {2b, 2b+1} so VT[b]
    // (4 MB) stays L2-resident on those XCDs.
    const int i = blockIdx.x;
    const int b = (i >> 1) & 3;
    const int rt = ((i >> 3) << 1) | (i & 1);   // row-tile 0..127
    const int m0 = rt * 32;

    float* Srow = S + ((size_t)b * Lq + m0) * Lk;
    const u16* VT = VTg + (size_t)b * (size_t)D * Lk;
    float* C = ctx + ((size_t)b * Lq + m0) * D;

    const int t = threadIdx.x, lane = t & 63, w = t >> 6;
    const int fr = lane & 15, fq = lane >> 4;

    // S staging: thread t handles row t>>4 (0..31), k-quad (t&15)*4
    const int srow = t >> 4;
    const int sk = (t & 15) * 4;
    const float mrow = rowM[(size_t)b * Lq + m0 + srow];
    const float inv  = rowI[(size_t)b * Lq + m0 + srow];
    const int aw = srow * 64 + (((sk >> 3) ^ (srow & 7)) * 8) + (sk & 4);

    // VT staging: call j covers rows j*64 + w*8 + (lane>>3); lane&7 is the
    // LDS chunk position; global k-chunk = pos ^ (row&7)  (row&7 == lane>>3)
    const int vrow = w * 8 + (lane >> 3);
    const int vck = (lane & 7) ^ (lane >> 3);
    const int swc = fr & 7;   // read-side XOR term

    f32x4 acc[2][4] = {};

    for (int kt = 0; kt < NT; ++kt) {
        const int k0 = kt * 64;
        if (kt) __syncthreads();

        // stage VT tile (8 x 4KB block-calls)
        #pragma unroll
        for (int j = 0; j < 8; ++j)
            gld16(VT + (size_t)(j * 64 + vrow) * Lk + k0 + vck * 8,
                  &sB[(j * 512 + w * 64) * 8]);

        // stage S: load, exp, write attn in place, pack bf16 into sA
        float4 v = *(const float4*)(Srow + (size_t)srow * Lk + k0 + sk);
        v.x = __expf(v.x - mrow) * inv;
        v.y = __expf(v.y - mrow) * inv;
        v.z = __expf(v.z - mrow) * inv;
        v.w = __expf(v.w - mrow) * inv;
        *(float4*)(Srow + (size_t)srow * Lk + k0 + sk) = v;
        uint2 h;
        h.x = pack2_bf16(v.x, v.y);
        h.y = pack2_bf16(v.z, v.w);
        *(uint2*)&sA[aw] = h;

        __syncthreads();

        #pragma unroll
        for (int ks = 0; ks < 2; ++ks) {
            const int pc = (ks * 4 + fq) ^ swc;
            bf16x8 af[2], bf[4];
            #pragma unroll
            for (int x = 0; x < 2; ++x)
                af[x] = *(const bf16x8*)&sA[(x * 16 + fr) * 64 + pc * 8];
            #pragma unroll
            for (int x = 0; x < 4; ++x)
                bf[x] = *(const bf16x8*)&sB[(w * 64 + x * 16 + fr) * 64 + pc * 8];
            #pragma unroll
            for (int mi = 0; mi < 2; ++mi)
                #pragma unroll
                for (int ni = 0; ni < 4; ++ni)
                    acc[mi][ni] = mfma16(af[mi], bf[ni], acc[mi][ni]);
        }
    }

    #pragma unroll
    for (int mi = 0; mi < 2; ++mi)
        #pragma unroll
        for (int ni = 0; ni < 4; ++ni)
            #pragma unroll
            for (int r = 0; r < 4; ++r)
                C[(size_t)(mi * 16 + fq * 4 + r) * D + w * 64 + ni * 16 + fr] =
                    acc[mi][ni][r];
}

// -------- softmax (fallback path): one row per wave, shfl-only -------------
__global__ __launch_bounds__(256)
void softmax_wave(float* __restrict__ S, u16* __restrict__ Pb)
{
    const size_t row = (size_t)blockIdx.x * 4 + (threadIdx.x >> 6);
    const int l = threadIdx.x & 63;
    float* p = S + row * (size_t)Lk;

    float4 v[16];
    #pragma unroll
    for (int j = 0; j < 16; ++j) v[j] = ((const float4*)p)[l + j * 64];

    float m = -3.0e38f;
    #pragma unroll
    for (int j = 0; j < 16; ++j)
        m = fmaxf(m, fmaxf(fmaxf(v[j].x, v[j].y), fmaxf(v[j].z, v[j].w)));
    #pragma unroll
    for (int off = 32; off > 0; off >>= 1) m = fmaxf(m, __shfl_xor(m, off));

    float s = 0.f;
    #pragma unroll
    for (int j = 0; j < 16; ++j) {
        v[j].x = __expf(v[j].x - m); s += v[j].x;
        v[j].y = __expf(v[j].y - m); s += v[j].y;
        v[j].z = __expf(v[j].z - m); s += v[j].z;
        v[j].w = __expf(v[j].w - m); s += v[j].w;
    }
    #pragma unroll
    for (int off = 32; off > 0; off >>= 1) s += __shfl_xor(s, off);

    const float inv = 1.0f / s;
    u16* prow = Pb ? Pb + row * (size_t)Lk : nullptr;
    #pragma unroll
    for (int j = 0; j < 16; ++j) {
        v[j].x *= inv; v[j].y *= inv; v[j].z *= inv; v[j].w *= inv;
        ((float4*)p)[l + j * 64] = v[j];
        if (prow) {
            ushort4 h = make_ushort4(f32_to_bf16_rne(v[j].x), f32_to_bf16_rne(v[j].y),
                                     f32_to_bf16_rne(v[j].z), f32_to_bf16_rne(v[j].w));
            ((ushort4*)prow)[l + j * 64] = h;
        }
    }
}

// ======================= round-2 fallback kernels ==========================
__global__ __launch_bounds__(256, 2)
void gemm1_r2(const float* __restrict__ Qg, const float* __restrict__ Vg,
              float* __restrict__ Sg)
{
    constexpr int K = D;
    __shared__ alignas(16) u16 sAhi[BM * LDA];
    __shared__ alignas(16) u16 sAlo[BM * LDA];
    __shared__ alignas(16) u16 sBhi[BN * LDA];
    __shared__ alignas(16) u16 sBlo[BN * LDA];

    const int b = blockIdx.z;
    const float* A  = Qg + (size_t)b * Lq * D;
    const float* Bp = Vg + (size_t)b * Lk * D;
    float* C = Sg + (size_t)b * Lq * Lk;

    const int m0 = blockIdx.y * BM;
    const int n0 = blockIdx.x * BN;
    const int t = threadIdx.x, lane = t & 63, wave = t >> 6;
    const int wm = (wave >> 1) * 64, wn = (wave & 1) * 64;
    const int fr = lane & 15, fq = lane >> 4;
    const int sm = t >> 3, sc = t & 7;

    f32x4 acc[4][4] = {};

    for (int k0 = 0; k0 < K; k0 += BK) {
        if (k0) __syncthreads();
        #pragma unroll
        for (int i = 0; i < 4; ++i) {
            const int m = sm + 32 * i;
            const float4 va = *(const float4*)(A  + (size_t)(m0 + m) * K + k0 + sc * 4);
            const float4 vb = *(const float4*)(Bp + (size_t)(n0 + m) * K + k0 + sc * 4);
            uint2 h, l;
            split2(va.x, va.y, h.x, l.x);
            split2(va.z, va.w, h.y, l.y);
            *(uint2*)&sAhi[m * LDA + sc * 4] = h;
            *(uint2*)&sAlo[m * LDA + sc * 4] = l;
            split2(vb.x, vb.y, h.x, l.x);
            split2(vb.z, vb.w, h.y, l.y);
            *(uint2*)&sBhi[m * LDA + sc * 4] = h;
            *(uint2*)&sBlo[m * LDA + sc * 4] = l;
        }
        __syncthreads();

        bf16x8 ah[4], al[4], bh[4], bl[4];
        #pragma unroll
        for (int x = 0; x < 4; ++x) {
            ah[x] = *(const bf16x8*)&sAhi[(wm + x * 16 + fr) * LDA + fq * 8];
            al[x] = *(const bf16x8*)&sAlo[(wm + x * 16 + fr) * LDA + fq * 8];
            bh[x] = *(const bf16x8*)&sBhi[(wn + x * 16 + fr) * LDA + fq * 8];
            bl[x] = *(const bf16x8*)&sBlo[(wn + x * 16 + fr) * LDA + fq * 8];
        }
        #pragma unroll
        for (int mi = 0; mi < 4; ++mi)
            #pragma unroll
            for (int ni = 0; ni < 4; ++ni) {
                acc[mi][ni] = __builtin_amdgcn_mfma_f32_16x16x32_bf16(ah[mi], bh[ni], acc[mi][ni], 0, 0, 0);
                acc[mi][ni] = __builtin_amdgcn_mfma_f32_16x16x32_bf16(ah[mi], bl[ni], acc[mi][ni], 0, 0, 0);
                acc[mi][ni] = __builtin_amdgcn_mfma_f32_16x16x32_bf16(al[mi], bh[ni], acc[mi][ni], 0, 0, 0);
            }
    }

    #pragma unroll
    for (int mi = 0; mi < 4; ++mi)
        #pragma unroll
        for (int ni = 0; ni < 4; ++ni)
            #pragma unroll
            for (int r = 0; r < 4; ++r) {
                const int row = m0 + wm + mi * 16 + fq * 4 + r;
                const int col = n0 + wn + ni * 16 + fr;
                C[(size_t)row * Lk + col] = acc[mi][ni][r];
            }
}

__global__ __launch_bounds__(256, 2)
void gemm2_r2(const float* __restrict__ Pg, const u16* __restrict__ VTg,
              float* __restrict__ Cg)
{
    constexpr int K = Lk;
    constexpr int N = D;
    __shared__ alignas(16) u16 sA[BM * LDA];
    __shared__ alignas(16) u16 sB[BN * LDA];

    const int b = blockIdx.z;
    const float* A  = Pg  + (size_t)b * Lq * Lk;
    const u16*   Bp = VTg + (size_t)b * (size_t)D * Lk;
    float* C = Cg + (size_t)b * Lq * D;

    const int m0 = blockIdx.y * BM;
    const int n0 = blockIdx.x * BN;
    const int t = threadIdx.x, lane = t & 63, wave = t >> 6;
    const int wm = (wave >> 1) * 64, wn = (wave & 1) * 64;
    const int fr = lane & 15, fq = lane >> 4;
    const int sm = t >> 3, sc = t & 7;
    const int bn = t >> 2, bc = t & 3;

    f32x4 acc[4][4] = {};

    for (int k0 = 0; k0 < K; k0 += BK) {
        if (k0) __syncthreads();
        #pragma unroll
        for (int i = 0; i < 4; ++i) {
            const int m = sm + 32 * i;
            const float4 va = *(const float4*)(A + (size_t)(m0 + m) * K + k0 + sc * 4);
            uint2 h;
            h.x = pack2_bf16(va.x, va.y);
            h.y = pack2_bf16(va.z, va.w);
            *(uint2*)&sA[m * LDA + sc * 4] = h;
        }
        #pragma unroll
        for (int i = 0; i < 2; ++i) {
            const int n = bn + 64 * i;
            const bf16x8 vb = *(const bf16x8*)(Bp + (size_t)(n0 + n) * K + k0 + bc * 8);
            *(bf16x8*)&sB[n * LDA + bc * 8] = vb;
        }
        __syncthreads();

        bf16x8 af[4], bf[4];
        #pragma unroll
        for (int x = 0; x < 4; ++x) {
            af[x] = *(const bf16x8*)&sA[(wm + x * 16 + fr) * LDA + fq * 8];
            bf[x] = *(const bf16x8*)&sB[(wn + x * 16 + fr) * LDA + fq * 8];
        }
        #pragma unroll
        for (int mi = 0; mi < 4; ++mi)
            #pragma unroll
            for (int ni = 0; ni < 4; ++ni)
                acc[mi][ni] = __builtin_amdgcn_mfma_f32_16x16x32_bf16(af[mi], bf[ni], acc[mi][ni], 0, 0, 0);
    }

    #pragma unroll
    for (int mi = 0; mi < 4; ++mi)
        #pragma unroll
        for (int ni = 0; ni < 4; ++ni)
            #pragma unroll
            for (int r = 0; r < 4; ++r) {
                const int row = m0 + wm + mi * 16 + fq * 4 + r;
                const int col = n0 + wn + ni * 16 + fr;
                C[(size_t)row * N + col] = acc[mi][ni][r];
            }
}

extern "C" void kernel_launch(void* const* d_in, const int* in_sizes, int n_in,
                              void* d_out, int out_size, void* d_ws, size_t ws_size,
                              hipStream_t stream)
{
    const float* Q = (const float*)d_in[0];   // [B, Lq, D]
    const float* V = (const float*)d_in[1];   // [B, Lk, D]
    float* ctx  = (float*)d_out;                              // [B, Lq, D]
    float* attn = (float*)d_out + (size_t)BATCH * Lq * D;     // [B, Lq, Lk]

    constexpr size_t NQ = (size_t)BATCH * Lq * D;    // 8,388,608 elems
    constexpr size_t NP = (size_t)BATCH * Lq * Lk;   // 67,108,864 elems
    const size_t need = (5 * NQ + NP) * sizeof(u16); // ~208 MiB

    if (ws_size >= need) {
        u16* Qhi = (u16*)d_ws;
        u16* Qlo = Qhi + NQ;
        u16* Vhi = Qlo + NQ;
        u16* Vlo = Vhi + NQ;
        u16* VT  = Vlo + NQ;
        u16* Pb  = VT  + NQ;

        // rowM/rowI (128 KiB) alias the head of the now-unused Pb region
        float* rowM = (float*)Pb;
        float* rowI = rowM + (size_t)BATCH * Lq;

        const int n4 = (int)(NQ / 4);
        split_qv_bf16<<<dim3(2 * n4 / 256), 256, 0, stream>>>(Q, V, Qhi, Qlo, Vhi, Vlo, n4);
        transpose_v_bf16<<<dim3(Lk / 32, D / 32, BATCH), 256, 0, stream>>>(V, VT);
        gemm1_8p<<<dim3(Lk / 256, Lq / 256, BATCH), 512, 0, stream>>>(Qhi, Qlo, Vhi, Vlo, attn);
        row_stats<<<dim3(BATCH * Lq / 4), 256, 0, stream>>>(attn, rowM, rowI);
        fused_pv<<<dim3(512), 512, 0, stream>>>(attn, VT, ctx, rowM, rowI);
    } else {
        // fallback: only needs 16.8 MiB for VT
        u16* VT = (u16*)d_ws;
        transpose_v_bf16<<<dim3(Lk / 32, D / 32, BATCH), 256, 0, stream>>>(V, VT);
        gemm1_r2<<<dim3(Lk / BN, Lq / BM, BATCH), 256, 0, stream>>>(Q, V, attn);
        softmax_wave<<<dim3(BATCH * Lq / 4), 256, 0, stream>>>(attn, nullptr);
        gemm2_r2<<<dim3(D / BN, Lq / BM, BATCH), 256, 0, stream>>>(attn, VT, ctx);
    }
}

// Round 5
// 747.832 us; speedup vs baseline: 1.0297x; 1.0297x over previous
//
#include <hip/hip_runtime.h>
#include <cstddef>
#include <cstdint>

typedef unsigned short u16;

constexpr int BATCH = 4;
constexpr int Lq = 4096;
constexpr int Lk = 4096;
constexpr int D  = 512;

constexpr int BM = 128, BN = 128, BK = 32;
constexpr int LDA = 40;   // fallback-path LDS stride

using bf16x8 = __attribute__((ext_vector_type(8))) short;
using f32x4  = __attribute__((ext_vector_type(4))) float;

__device__ inline u16 f32_to_bf16_rne(float x) {
    uint32_t u = __builtin_bit_cast(uint32_t, x);
    u += 0x7fff + ((u >> 16) & 1);
    return (u16)(u >> 16);
}
__device__ inline float bf16_bits_to_f32(u16 h) {
    uint32_t u = ((uint32_t)h) << 16;
    return __builtin_bit_cast(float, u);
}
__device__ inline void split2(float x, float y, uint32_t& hi, uint32_t& lo) {
    u16 hx = f32_to_bf16_rne(x);
    u16 hy = f32_to_bf16_rne(y);
    u16 lx = f32_to_bf16_rne(x - bf16_bits_to_f32(hx));
    u16 ly = f32_to_bf16_rne(y - bf16_bits_to_f32(hy));
    hi = (uint32_t)hx | ((uint32_t)hy << 16);
    lo = (uint32_t)lx | ((uint32_t)ly << 16);
}
__device__ inline uint32_t pack2_bf16(float x, float y) {
    return (uint32_t)f32_to_bf16_rne(x) | ((uint32_t)f32_to_bf16_rne(y) << 16);
}
// async global->LDS, 16B/lane; LDS dest is wave-uniform base + lane*16
__device__ inline void gld16(const u16* g, u16* l) {
    __builtin_amdgcn_global_load_lds(
        (const __attribute__((address_space(1))) void*)g,
        (__attribute__((address_space(3))) void*)l, 16, 0, 0);
}
__device__ inline f32x4 mfma16(bf16x8 a, bf16x8 b, f32x4 c) {
    return __builtin_amdgcn_mfma_f32_16x16x32_bf16(a, b, c, 0, 0, 0);
}

// ------- pre-split both tensors: fp32 -> bf16 hi + bf16 lo (one launch) ----
__global__ __launch_bounds__(256)
void split_qv_bf16(const float* __restrict__ Q, const float* __restrict__ V,
                   u16* __restrict__ Qhi, u16* __restrict__ Qlo,
                   u16* __restrict__ Vhi, u16* __restrict__ Vlo, int n4)
{
    int i = blockIdx.x * 256 + threadIdx.x;
    const float* src;
    u16 *hi, *lo;
    if (i < n4) { src = Q; hi = Qhi; lo = Qlo; }
    else        { src = V; hi = Vhi; lo = Vlo; i -= n4; }
    const float4 v = ((const float4*)src)[i];
    uint2 h, l;
    split2(v.x, v.y, h.x, l.x);
    split2(v.z, v.w, h.y, l.y);
    ((uint2*)hi)[i] = h;
    ((uint2*)lo)[i] = l;
}

// ---------------- V^T (bf16) into workspace: VT[b][d][lk] -------------------
__global__ __launch_bounds__(256)
void transpose_v_bf16(const float* __restrict__ V, u16* __restrict__ VT)
{
    __shared__ float tile[32][33];
    const int b = blockIdx.z;
    const float* in = V + (size_t)b * Lk * D;
    u16* out = VT + (size_t)b * D * Lk;
    const int lk0 = blockIdx.x * 32;
    const int d0  = blockIdx.y * 32;
    const int c  = threadIdx.x & 31;
    const int r0 = threadIdx.x >> 5;
    #pragma unroll
    for (int i = 0; i < 4; ++i) {
        const int r = r0 + 8 * i;
        tile[r][c] = in[(size_t)(lk0 + r) * D + d0 + c];
    }
    __syncthreads();
    #pragma unroll
    for (int i = 0; i < 4; ++i) {
        const int r = r0 + 8 * i;
        out[(size_t)(d0 + r) * Lk + lk0 + c] = f32_to_bf16_rne(tile[c][r]);
    }
}

// ===== GEMM1: S = Q@V^T, 256x256 tile, 8 waves, 4-phase/K-tile pipeline ====
// (round-1 version, verified 201-204 us / 0 bank conflicts — unchanged)
__global__ __launch_bounds__(512, 2)
void gemm1_8p(const u16* __restrict__ Qhi, const u16* __restrict__ Qlo,
              const u16* __restrict__ Vhi, const u16* __restrict__ Vlo,
              float* __restrict__ Sg)
{
    constexpr int K  = D;        // 512
    constexpr int NT = K / 32;   // 16 K-tiles
    // [buf][Ahi|Alo|Bhi|Blo][256 rows][32 k] u16 = 128 KiB
    __shared__ u16 lds[2 * 4 * 8192];

    const int b = blockIdx.z;
    const u16* Ah = Qhi + (size_t)b * Lq * K;
    const u16* Al = Qlo + (size_t)b * Lq * K;
    const u16* Bh = Vhi + (size_t)b * Lk * K;
    const u16* Bl = Vlo + (size_t)b * Lk * K;
    float* C = Sg + (size_t)b * Lq * Lk;

    const int m0 = blockIdx.y * 256;
    const int n0 = blockIdx.x * 256;
    const int t = threadIdx.x, lane = t & 63, w = t >> 6;
    const int wm = (w >> 2) * 128, wn = (w & 3) * 64;
    const int fr = lane & 15, fq = lane >> 4;

    const int cg   = (lane & 3) ^ ((lane >> 3) & 3);   // inverse-swizzled k-chunk
    const int rsub = lane >> 2;
    const int offA0 = (m0 + w * 32 + rsub) * K + cg * 8;
    const int offA1 = offA0 + 16 * K;
    const int offB0 = (n0 + w * 32 + rsub) * K + cg * 8;
    const int offB1 = offB0 + 16 * K;
    const int ch = w * 1024;   // u16: this wave's chunk base

    const int swzc = fq ^ ((fr >> 1) & 3);
    const int aRd = (wm + fr) * 64 + swzc * 16;   // bytes within Ahi region
    const int bRd = (wn + fr) * 64 + swzc * 16;   // bytes within Bhi region

    f32x4 acc[8][4] = {};
    bf16x8 aH[4], aL[4], bH[4], bL[4];

    // prologue: stage K-tile 0 into buf 0
    {
        u16* a = &lds[ch];
        gld16(Ah + offA0, a);
        gld16(Ah + offA1, a + 512);
        gld16(Al + offA0, a + 8192);
        gld16(Al + offA1, a + 8192 + 512);
        u16* v = &lds[16384 + ch];
        gld16(Bh + offB0, v);
        gld16(Bh + offB1, v + 512);
        gld16(Bl + offB0, v + 8192);
        gld16(Bl + offB1, v + 8192 + 512);
    }
    asm volatile("s_waitcnt vmcnt(0)" ::: "memory");
    __builtin_amdgcn_s_barrier();
    __builtin_amdgcn_sched_barrier(0);

    for (int kt = 0; kt < NT; ++kt) {
        const int cur = kt & 1;
        const char* ls = (const char*)lds + cur * 65536;
        const int kn = (kt + 1) * 32;
        const int nb = (cur ^ 1) * 32768;   // u16 index of next buffer

        // ---- phase 0: frags A(mh0) + B(n0,n1); prefetch next A ----
        #pragma unroll
        for (int m = 0; m < 4; ++m) {
            aH[m] = *(const bf16x8*)(ls + aRd + m * 1024);
            aL[m] = *(const bf16x8*)(ls + 16384 + aRd + m * 1024);
        }
        #pragma unroll
        for (int n = 0; n < 2; ++n) {
            bH[n] = *(const bf16x8*)(ls + 32768 + bRd + n * 1024);
            bL[n] = *(const bf16x8*)(ls + 49152 + bRd + n * 1024);
        }
        if (kt < NT - 1) {
            u16* a = &lds[nb + ch];
            gld16(Ah + offA0 + kn, a);
            gld16(Ah + offA1 + kn, a + 512);
            gld16(Al + offA0 + kn, a + 8192);
            gld16(Al + offA1 + kn, a + 8192 + 512);
        }
        __builtin_amdgcn_s_barrier();
        asm volatile("s_waitcnt lgkmcnt(0)" ::: "memory");
        __builtin_amdgcn_sched_barrier(0);
        __builtin_amdgcn_s_setprio(1);
        #pragma unroll
        for (int m = 0; m < 4; ++m)
            #pragma unroll
            for (int n = 0; n < 2; ++n) {
                acc[m][n] = mfma16(aH[m], bH[n], acc[m][n]);
                acc[m][n] = mfma16(aH[m], bL[n], acc[m][n]);
                acc[m][n] = mfma16(aL[m], bH[n], acc[m][n]);
            }
        __builtin_amdgcn_s_setprio(0);
        __builtin_amdgcn_s_barrier();
        __builtin_amdgcn_sched_barrier(0);

        // ---- phase 1: frags B(n2,n3); prefetch next B ----
        #pragma unroll
        for (int n = 2; n < 4; ++n) {
            bH[n] = *(const bf16x8*)(ls + 32768 + bRd + n * 1024);
            bL[n] = *(const bf16x8*)(ls + 49152 + bRd + n * 1024);
        }
        if (kt < NT - 1) {
            u16* v = &lds[nb + 16384 + ch];
            gld16(Bh + offB0 + kn, v);
            gld16(Bh + offB1 + kn, v + 512);
            gld16(Bl + offB0 + kn, v + 8192);
            gld16(Bl + offB1 + kn, v + 8192 + 512);
        }
        __builtin_amdgcn_s_barrier();
        asm volatile("s_waitcnt lgkmcnt(0)" ::: "memory");
        __builtin_amdgcn_sched_barrier(0);
        __builtin_amdgcn_s_setprio(1);
        #pragma unroll
        for (int m = 0; m < 4; ++m)
            #pragma unroll
            for (int n = 2; n < 4; ++n) {
                acc[m][n] = mfma16(aH[m], bH[n], acc[m][n]);
                acc[m][n] = mfma16(aH[m], bL[n], acc[m][n]);
                acc[m][n] = mfma16(aL[m], bH[n], acc[m][n]);
            }
        __builtin_amdgcn_s_setprio(0);
        __builtin_amdgcn_s_barrier();
        __builtin_amdgcn_sched_barrier(0);

        // ---- phase 2: frags A(mh1) ----
        #pragma unroll
        for (int m = 0; m < 4; ++m) {
            aH[m] = *(const bf16x8*)(ls + 4096 + aRd + m * 1024);
            aL[m] = *(const bf16x8*)(ls + 16384 + 4096 + aRd + m * 1024);
        }
        __builtin_amdgcn_s_barrier();
        asm volatile("s_waitcnt lgkmcnt(0)" ::: "memory");
        __builtin_amdgcn_sched_barrier(0);
        __builtin_amdgcn_s_setprio(1);
        #pragma unroll
        for (int m = 0; m < 4; ++m)
            #pragma unroll
            for (int n = 0; n < 2; ++n) {
                acc[4 + m][n] = mfma16(aH[m], bH[n], acc[4 + m][n]);
                acc[4 + m][n] = mfma16(aH[m], bL[n], acc[4 + m][n]);
                acc[4 + m][n] = mfma16(aL[m], bH[n], acc[4 + m][n]);
            }
        __builtin_amdgcn_s_setprio(0);
        __builtin_amdgcn_s_barrier();
        __builtin_amdgcn_sched_barrier(0);

        // ---- phase 3: last quadrant; tile-boundary drain (only vmcnt) ----
        __builtin_amdgcn_s_setprio(1);
        #pragma unroll
        for (int m = 0; m < 4; ++m)
            #pragma unroll
            for (int n = 2; n < 4; ++n) {
                acc[4 + m][n] = mfma16(aH[m], bH[n], acc[4 + m][n]);
                acc[4 + m][n] = mfma16(aH[m], bL[n], acc[4 + m][n]);
                acc[4 + m][n] = mfma16(aL[m], bH[n], acc[4 + m][n]);
            }
        __builtin_amdgcn_s_setprio(0);
        asm volatile("s_waitcnt vmcnt(0)" ::: "memory");
        __builtin_amdgcn_s_barrier();
        __builtin_amdgcn_sched_barrier(0);
    }

    const int rowb = m0 + wm + fq * 4;
    const int colb = n0 + wn + fr;
    #pragma unroll
    for (int mi = 0; mi < 8; ++mi)
        #pragma unroll
        for (int ni = 0; ni < 4; ++ni)
            #pragma unroll
            for (int r = 0; r < 4; ++r)
                C[(size_t)(rowb + mi * 16 + r) * Lk + colb + ni * 16] = acc[mi][ni][r];
}

// ===== fused stats + finalize + PV =========================================
// 256 blocks (1/CU), 512 thr / 8 waves, 64 q-rows x all 512 ctx-cols.
// Prologue: per-row max/sumexp (replaces row_stats kernel).
// Main loop: double-buffered K-steps of 64; per step: store attn (regs),
// prefetch next VT (gld16, src-swizzled) + next S (regs), MFMA current,
// exp-process next S into sA[nxt] (padded stride 72), one barrier drain.
__global__ __launch_bounds__(512, 2)
void fused_spv(float* __restrict__ S, const u16* __restrict__ VTg,
               float* __restrict__ ctx)
{
    constexpr int NT = Lk / 64;   // 64 K-steps
    __shared__ u16 sB[2][512 * 64];   // 2 x 64 KB
    __shared__ u16 sA[2][64 * 72];    // 2 x 9 KB (stride 72 = +8 pad)
    __shared__ float mro[64], iro[64];

    const int i = blockIdx.x;        // 256 blocks
    const int b = i >> 6;
    const int m0 = (i & 63) * 64;

    float* Srow = S + ((size_t)b * Lq + m0) * Lk;
    const u16* VT = VTg + (size_t)b * (size_t)D * Lk;
    float* C = ctx + ((size_t)b * Lq + m0) * D;

    const int t = threadIdx.x, lane = t & 63, w = t >> 6;
    const int fr = lane & 15, fq = lane >> 4;

    // VT staging (proven r3 pattern): row-group j*64 + w*8 + (lane>>3),
    // LDS slot lane&7 holds global k-octet (lane&7)^(row&7)
    const int vrow = w * 8 + (lane >> 3);
    const int vck  = (lane & 7) ^ (lane >> 3);
    const int swc  = fr & 7;          // read-side XOR term

    // S processing: thread handles row sr, octet so (8 consecutive k)
    const int sr = t >> 3, so = t & 7;

    // ---- issue VT stage for kt=0 early (drained at first barrier) ----
    #pragma unroll
    for (int j = 0; j < 8; ++j)
        gld16(VT + (size_t)(j * 64 + vrow) * Lk + vck * 8,
              &sB[0][(j * 512 + w * 64) * 8]);

    // ---- stats: wave w reduces rows w*8 .. w*8+7 (same order as row_stats)
    #pragma unroll 1
    for (int rr = 0; rr < 8; ++rr) {
        const int r = w * 8 + rr;
        const float* p = Srow + (size_t)r * Lk;
        float4 v[16];
        #pragma unroll
        for (int j = 0; j < 16; ++j) v[j] = ((const float4*)p)[lane + j * 64];
        float m = -3.0e38f;
        #pragma unroll
        for (int j = 0; j < 16; ++j)
            m = fmaxf(m, fmaxf(fmaxf(v[j].x, v[j].y), fmaxf(v[j].z, v[j].w)));
        #pragma unroll
        for (int off = 32; off > 0; off >>= 1) m = fmaxf(m, __shfl_xor(m, off));
        float s = 0.f;
        #pragma unroll
        for (int j = 0; j < 16; ++j) {
            s += __expf(v[j].x - m);
            s += __expf(v[j].y - m);
            s += __expf(v[j].z - m);
            s += __expf(v[j].w - m);
        }
        #pragma unroll
        for (int off = 32; off > 0; off >>= 1) s += __shfl_xor(s, off);
        if (lane == 0) { mro[r] = m; iro[r] = 1.0f / s; }
    }
    __syncthreads();                       // stats visible; sB[0] drained
    const float mr_ = mro[sr], ir_ = iro[sr];

    // ---- prologue: S(0) -> sv regs + sA[0] ----
    float4 sv0, sv1;
    {
        const float4 a = *(const float4*)(Srow + (size_t)sr * Lk + so * 8);
        const float4 c2 = *(const float4*)(Srow + (size_t)sr * Lk + so * 8 + 4);
        sv0.x = __expf(a.x - mr_) * ir_;  sv0.y = __expf(a.y - mr_) * ir_;
        sv0.z = __expf(a.z - mr_) * ir_;  sv0.w = __expf(a.w - mr_) * ir_;
        sv1.x = __expf(c2.x - mr_) * ir_; sv1.y = __expf(c2.y - mr_) * ir_;
        sv1.z = __expf(c2.z - mr_) * ir_; sv1.w = __expf(c2.w - mr_) * ir_;
        uint4 hq;
        hq.x = pack2_bf16(sv0.x, sv0.y); hq.y = pack2_bf16(sv0.z, sv0.w);
        hq.z = pack2_bf16(sv1.x, sv1.y); hq.w = pack2_bf16(sv1.z, sv1.w);
        *(uint4*)&sA[0][sr * 72 + so * 8] = hq;
    }
    __syncthreads();                       // sA[0] visible

    f32x4 acc[4][4] = {};

    for (int kt = 0; kt < NT; ++kt) {
        const int cur = kt & 1, nxt = cur ^ 1;
        const int k0 = kt * 64;

        // attn store for this step's P values (ack covered by MFMA phase)
        *(float4*)(Srow + (size_t)sr * Lk + k0 + so * 8)     = sv0;
        *(float4*)(Srow + (size_t)sr * Lk + k0 + so * 8 + 4) = sv1;

        float4 la, lb;
        if (kt + 1 < NT) {
            const int kn = k0 + 64;
            #pragma unroll
            for (int j = 0; j < 8; ++j)
                gld16(VT + (size_t)(j * 64 + vrow) * Lk + kn + vck * 8,
                      &sB[nxt][(j * 512 + w * 64) * 8]);
            la = *(const float4*)(Srow + (size_t)sr * Lk + kn + so * 8);
            lb = *(const float4*)(Srow + (size_t)sr * Lk + kn + so * 8 + 4);
        }

        __builtin_amdgcn_s_setprio(1);
        #pragma unroll
        for (int ks = 0; ks < 2; ++ks) {
            const int oc = ks * 4 + fq;
            bf16x8 af[4], bf[4];
            #pragma unroll
            for (int x = 0; x < 4; ++x)
                af[x] = *(const bf16x8*)&sA[cur][(x * 16 + fr) * 72 + oc * 8];
            #pragma unroll
            for (int x = 0; x < 4; ++x)
                bf[x] = *(const bf16x8*)&sB[cur][(w * 64 + x * 16 + fr) * 64 + (oc ^ swc) * 8];
            #pragma unroll
            for (int mi = 0; mi < 4; ++mi)
                #pragma unroll
                for (int ni = 0; ni < 4; ++ni)
                    acc[mi][ni] = mfma16(af[mi], bf[ni], acc[mi][ni]);
        }
        __builtin_amdgcn_s_setprio(0);

        if (kt + 1 < NT) {
            sv0.x = __expf(la.x - mr_) * ir_;  sv0.y = __expf(la.y - mr_) * ir_;
            sv0.z = __expf(la.z - mr_) * ir_;  sv0.w = __expf(la.w - mr_) * ir_;
            sv1.x = __expf(lb.x - mr_) * ir_;  sv1.y = __expf(lb.y - mr_) * ir_;
            sv1.z = __expf(lb.z - mr_) * ir_;  sv1.w = __expf(lb.w - mr_) * ir_;
            uint4 hq;
            hq.x = pack2_bf16(sv0.x, sv0.y); hq.y = pack2_bf16(sv0.z, sv0.w);
            hq.z = pack2_bf16(sv1.x, sv1.y); hq.w = pack2_bf16(sv1.z, sv1.w);
            *(uint4*)&sA[nxt][sr * 72 + so * 8] = hq;
        }
        __syncthreads();   // drains gld16(nxt) + attn stores; sA[nxt] visible
    }

    #pragma unroll
    for (int mi = 0; mi < 4; ++mi)
        #pragma unroll
        for (int ni = 0; ni < 4; ++ni)
            #pragma unroll
            for (int r = 0; r < 4; ++r)
                C[(size_t)(mi * 16 + fq * 4 + r) * D + w * 64 + ni * 16 + fr] =
                    acc[mi][ni][r];
}

// -------- softmax (fallback path): one row per wave, shfl-only -------------
__global__ __launch_bounds__(256)
void softmax_wave(float* __restrict__ S, u16* __restrict__ Pb)
{
    const size_t row = (size_t)blockIdx.x * 4 + (threadIdx.x >> 6);
    const int l = threadIdx.x & 63;
    float* p = S + row * (size_t)Lk;

    float4 v[16];
    #pragma unroll
    for (int j = 0; j < 16; ++j) v[j] = ((const float4*)p)[l + j * 64];

    float m = -3.0e38f;
    #pragma unroll
    for (int j = 0; j < 16; ++j)
        m = fmaxf(m, fmaxf(fmaxf(v[j].x, v[j].y), fmaxf(v[j].z, v[j].w)));
    #pragma unroll
    for (int off = 32; off > 0; off >>= 1) m = fmaxf(m, __shfl_xor(m, off));

    float s = 0.f;
    #pragma unroll
    for (int j = 0; j < 16; ++j) {
        v[j].x = __expf(v[j].x - m); s += v[j].x;
        v[j].y = __expf(v[j].y - m); s += v[j].y;
        v[j].z = __expf(v[j].z - m); s += v[j].z;
        v[j].w = __expf(v[j].w - m); s += v[j].w;
    }
    #pragma unroll
    for (int off = 32; off > 0; off >>= 1) s += __shfl_xor(s, off);

    const float inv = 1.0f / s;
    u16* prow = Pb ? Pb + row * (size_t)Lk : nullptr;
    #pragma unroll
    for (int j = 0; j < 16; ++j) {
        v[j].x *= inv; v[j].y *= inv; v[j].z *= inv; v[j].w *= inv;
        ((float4*)p)[l + j * 64] = v[j];
        if (prow) {
            ushort4 h = make_ushort4(f32_to_bf16_rne(v[j].x), f32_to_bf16_rne(v[j].y),
                                     f32_to_bf16_rne(v[j].z), f32_to_bf16_rne(v[j].w));
            ((ushort4*)prow)[l + j * 64] = h;
        }
    }
}

// ======================= fallback kernels ==================================
__global__ __launch_bounds__(256, 2)
void gemm1_r2(const float* __restrict__ Qg, const float* __restrict__ Vg,
              float* __restrict__ Sg)
{
    constexpr int K = D;
    __shared__ alignas(16) u16 sAhi[BM * LDA];
    __shared__ alignas(16) u16 sAlo[BM * LDA];
    __shared__ alignas(16) u16 sBhi[BN * LDA];
    __shared__ alignas(16) u16 sBlo[BN * LDA];

    const int b = blockIdx.z;
    const float* A  = Qg + (size_t)b * Lq * D;
    const float* Bp = Vg + (size_t)b * Lk * D;
    float* C = Sg + (size_t)b * Lq * Lk;

    const int m0 = blockIdx.y * BM;
    const int n0 = blockIdx.x * BN;
    const int t = threadIdx.x, lane = t & 63, wave = t >> 6;
    const int wm = (wave >> 1) * 64, wn = (wave & 1) * 64;
    const int fr = lane & 15, fq = lane >> 4;
    const int sm = t >> 3, sc = t & 7;

    f32x4 acc[4][4] = {};

    for (int k0 = 0; k0 < K; k0 += BK) {
        if (k0) __syncthreads();
        #pragma unroll
        for (int i = 0; i < 4; ++i) {
            const int m = sm + 32 * i;
            const float4 va = *(const float4*)(A  + (size_t)(m0 + m) * K + k0 + sc * 4);
            const float4 vb = *(const float4*)(Bp + (size_t)(n0 + m) * K + k0 + sc * 4);
            uint2 h, l;
            split2(va.x, va.y, h.x, l.x);
            split2(va.z, va.w, h.y, l.y);
            *(uint2*)&sAhi[m * LDA + sc * 4] = h;
            *(uint2*)&sAlo[m * LDA + sc * 4] = l;
            split2(vb.x, vb.y, h.x, l.x);
            split2(vb.z, vb.w, h.y, l.y);
            *(uint2*)&sBhi[m * LDA + sc * 4] = h;
            *(uint2*)&sBlo[m * LDA + sc * 4] = l;
        }
        __syncthreads();

        bf16x8 ah[4], al[4], bh[4], bl[4];
        #pragma unroll
        for (int x = 0; x < 4; ++x) {
            ah[x] = *(const bf16x8*)&sAhi[(wm + x * 16 + fr) * LDA + fq * 8];
            al[x] = *(const bf16x8*)&sAlo[(wm + x * 16 + fr) * LDA + fq * 8];
            bh[x] = *(const bf16x8*)&sBhi[(wn + x * 16 + fr) * LDA + fq * 8];
            bl[x] = *(const bf16x8*)&sBlo[(wn + x * 16 + fr) * LDA + fq * 8];
        }
        #pragma unroll
        for (int mi = 0; mi < 4; ++mi)
            #pragma unroll
            for (int ni = 0; ni < 4; ++ni) {
                acc[mi][ni] = __builtin_amdgcn_mfma_f32_16x16x32_bf16(ah[mi], bh[ni], acc[mi][ni], 0, 0, 0);
                acc[mi][ni] = __builtin_amdgcn_mfma_f32_16x16x32_bf16(ah[mi], bl[ni], acc[mi][ni], 0, 0, 0);
                acc[mi][ni] = __builtin_amdgcn_mfma_f32_16x16x32_bf16(al[mi], bh[ni], acc[mi][ni], 0, 0, 0);
            }
    }

    #pragma unroll
    for (int mi = 0; mi < 4; ++mi)
        #pragma unroll
        for (int ni = 0; ni < 4; ++ni)
            #pragma unroll
            for (int r = 0; r < 4; ++r) {
                const int row = m0 + wm + mi * 16 + fq * 4 + r;
                const int col = n0 + wn + ni * 16 + fr;
                C[(size_t)row * Lk + col] = acc[mi][ni][r];
            }
}

__global__ __launch_bounds__(256, 2)
void gemm2_r2(const float* __restrict__ Pg, const u16* __restrict__ VTg,
              float* __restrict__ Cg)
{
    constexpr int K = Lk;
    constexpr int N = D;
    __shared__ alignas(16) u16 sA[BM * LDA];
    __shared__ alignas(16) u16 sB[BN * LDA];

    const int b = blockIdx.z;
    const float* A  = Pg  + (size_t)b * Lq * Lk;
    const u16*   Bp = VTg + (size_t)b * (size_t)D * Lk;
    float* C = Cg + (size_t)b * Lq * D;

    const int m0 = blockIdx.y * BM;
    const int n0 = blockIdx.x * BN;
    const int t = threadIdx.x, lane = t & 63, wave = t >> 6;
    const int wm = (wave >> 1) * 64, wn = (wave & 1) * 64;
    const int fr = lane & 15, fq = lane >> 4;
    const int sm = t >> 3, sc = t & 7;
    const int bn = t >> 2, bc = t & 3;

    f32x4 acc[4][4] = {};

    for (int k0 = 0; k0 < K; k0 += BK) {
        if (k0) __syncthreads();
        #pragma unroll
        for (int i = 0; i < 4; ++i) {
            const int m = sm + 32 * i;
            const float4 va = *(const float4*)(A + (size_t)(m0 + m) * K + k0 + sc * 4);
            uint2 h;
            h.x = pack2_bf16(va.x, va.y);
            h.y = pack2_bf16(va.z, va.w);
            *(uint2*)&sA[m * LDA + sc * 4] = h;
        }
        #pragma unroll
        for (int i = 0; i < 2; ++i) {
            const int n = bn + 64 * i;
            const bf16x8 vb = *(const bf16x8*)(Bp + (size_t)(n0 + n) * K + k0 + bc * 8);
            *(bf16x8*)&sB[n * LDA + bc * 8] = vb;
        }
        __syncthreads();

        bf16x8 af[4], bf[4];
        #pragma unroll
        for (int x = 0; x < 4; ++x) {
            af[x] = *(const bf16x8*)&sA[(wm + x * 16 + fr) * LDA + fq * 8];
            bf[x] = *(const bf16x8*)&sB[(wn + x * 16 + fr) * LDA + fq * 8];
        }
        #pragma unroll
        for (int mi = 0; mi < 4; ++mi)
            #pragma unroll
            for (int ni = 0; ni < 4; ++ni)
                acc[mi][ni] = __builtin_amdgcn_mfma_f32_16x16x32_bf16(af[mi], bf[ni], acc[mi][ni], 0, 0, 0);
    }

    #pragma unroll
    for (int mi = 0; mi < 4; ++mi)
        #pragma unroll
        for (int ni = 0; ni < 4; ++ni)
            #pragma unroll
            for (int r = 0; r < 4; ++r) {
                const int row = m0 + wm + mi * 16 + fq * 4 + r;
                const int col = n0 + wn + ni * 16 + fr;
                C[(size_t)row * N + col] = acc[mi][ni][r];
            }
}

extern "C" void kernel_launch(void* const* d_in, const int* in_sizes, int n_in,
                              void* d_out, int out_size, void* d_ws, size_t ws_size,
                              hipStream_t stream)
{
    const float* Q = (const float*)d_in[0];   // [B, Lq, D]
    const float* V = (const float*)d_in[1];   // [B, Lk, D]
    float* ctx  = (float*)d_out;                              // [B, Lq, D]
    float* attn = (float*)d_out + (size_t)BATCH * Lq * D;     // [B, Lq, Lk]

    constexpr size_t NQ = (size_t)BATCH * Lq * D;    // 8,388,608 elems
    constexpr size_t NP = (size_t)BATCH * Lq * Lk;   // 67,108,864 elems
    const size_t need = (5 * NQ + NP) * sizeof(u16); // ~208 MiB

    if (ws_size >= need) {
        u16* Qhi = (u16*)d_ws;
        u16* Qlo = Qhi + NQ;
        u16* Vhi = Qlo + NQ;
        u16* Vlo = Vhi + NQ;
        u16* VT  = Vlo + NQ;

        const int n4 = (int)(NQ / 4);
        split_qv_bf16<<<dim3(2 * n4 / 256), 256, 0, stream>>>(Q, V, Qhi, Qlo, Vhi, Vlo, n4);
        transpose_v_bf16<<<dim3(Lk / 32, D / 32, BATCH), 256, 0, stream>>>(V, VT);
        gemm1_8p<<<dim3(Lk / 256, Lq / 256, BATCH), 512, 0, stream>>>(Qhi, Qlo, Vhi, Vlo, attn);
        fused_spv<<<dim3(256), 512, 0, stream>>>(attn, VT, ctx);
    } else {
        // fallback: only needs 16.8 MiB for VT
        u16* VT = (u16*)d_ws;
        transpose_v_bf16<<<dim3(Lk / 32, D / 32, BATCH), 256, 0, stream>>>(V, VT);
        gemm1_r2<<<dim3(Lk / BN, Lq / BM, BATCH), 256, 0, stream>>>(Q, V, attn);
        softmax_wave<<<dim3(BATCH * Lq / 4), 256, 0, stream>>>(attn, nullptr);
        gemm2_r2<<<dim3(D / BN, Lq / BM, BATCH), 256, 0, stream>>>(attn, VT, ctx);
    }
}